// Round 1
// baseline (592.167 us; speedup 1.0000x reference)
//
#include <hip/hip_runtime.h>
#include <hip/hip_bf16.h>

// M=2048, A=64, E=128, H=256, bond types=4, atom types=118
typedef __bf16 bf16x8 __attribute__((ext_vector_type(8)));
typedef float f32x16 __attribute__((ext_vector_type(16)));

__device__ inline unsigned short f2bf(float f) {
  __hip_bfloat16 h = __float2bfloat16(f);
  return *reinterpret_cast<unsigned short*>(&h);
}
__device__ inline unsigned pack2bf(float a, float b) {
  return (unsigned)f2bf(a) | ((unsigned)f2bf(b) << 16);
}
__device__ inline uint2 pack4bf(float a, float b, float c, float d) {
  uint2 r; r.x = pack2bf(a, b); r.y = pack2bf(c, d); return r;
}
__device__ inline bf16x8 as_bf16x8(uint4 v) { return __builtin_bit_cast(bf16x8, v); }
__device__ inline f32x16 mfma16(bf16x8 a, bf16x8 b, f32x16 c) {
  return __builtin_amdgcn_mfma_f32_32x32x16_bf16(a, b, c, 0, 0, 0);
}

// ---------------------------------------------------------------------------
// Pack weights to bf16 in fragment-ready layout:
//   chunk kk (16 k's), element (n, dk) at ushort index (kk*N + n)*16 + dk
//   value = W[kk*16+dk][n] (row-major src, stride Nreal), 0-pad n >= Nreal.
// Block ranges: Wp1[0,256) Wp2[256,512) Wa1[512,768) Wb1[768,1280)
//               Wa2[1280,1408) (N=128, Nreal=118)  Wb2[1408,1440) (N=32, Nreal=4)
// ---------------------------------------------------------------------------
__global__ __launch_bounds__(256) void k_pack(
    const float* __restrict__ wp1, const float* __restrict__ wp2,
    const float* __restrict__ wa1, const float* __restrict__ wb1,
    const float* __restrict__ wa2, const float* __restrict__ wb2,
    unsigned short* __restrict__ dp1, unsigned short* __restrict__ dp2,
    unsigned short* __restrict__ da1, unsigned short* __restrict__ db1,
    unsigned short* __restrict__ da2, unsigned short* __restrict__ db2,
    float* __restrict__ accum)
{
  int b = blockIdx.x, tid = threadIdx.x;
  if (b == 0 && tid < 8) accum[tid] = 0.f;
  const float* src; unsigned short* dst; int e, logN, Nreal;
  if (b < 256)       { src = wp1; dst = dp1; e = b * 256 + tid;          logN = 8; Nreal = 256; }
  else if (b < 512)  { src = wp2; dst = dp2; e = (b - 256) * 256 + tid;  logN = 8; Nreal = 256; }
  else if (b < 768)  { src = wa1; dst = da1; e = (b - 512) * 256 + tid;  logN = 8; Nreal = 256; }
  else if (b < 1280) { src = wb1; dst = db1; e = (b - 768) * 256 + tid;  logN = 8; Nreal = 256; }
  else if (b < 1408) { src = wa2; dst = da2; e = (b - 1280) * 256 + tid; logN = 7; Nreal = 118; }
  else               { src = wb2; dst = db2; e = (b - 1408) * 256 + tid; logN = 5; Nreal = 4;   }
  int dk = e & 15;
  int rest = e >> 4;
  int n = rest & ((1 << logN) - 1);
  int kk = rest >> logN;
  int k = kk * 16 + dk;
  float v = (n < Nreal) ? src[k * Nreal + n] : 0.f;
  dst[e] = f2bf(v);
}

// ---------------------------------------------------------------------------
// proj = relu(node @ Wp1 + bp1) @ Wp2 + bp2   -> bf16 [131072][256]
// Block: 128 rows, 4 waves (2 col-halves x 2 row-halves), wave = 128 cols x 64 rows.
// Swapped MFMA: A = W (M-dim = out cols), B = X (N-dim = rows).
// D: x-row = lane&31, w-col = (q&3)+8*(q>>2)+4*(lane>>5).
// ---------------------------------------------------------------------------
__global__ __launch_bounds__(256, 2) void k_proj(
    const float* __restrict__ node,
    const unsigned short* __restrict__ w1p, const float* __restrict__ b1,
    const unsigned short* __restrict__ w2p, const float* __restrict__ b2,
    unsigned short* __restrict__ proj)
{
  __shared__ __align__(16) unsigned char sm[65536]; // union: X[128][256]bf16 / hidden[128][256]bf16
  const int tid = threadIdx.x;
  const int lane = tid & 63;
  const int w = tid >> 6;
  const int l31 = lane & 31;
  const int h = lane >> 5;
  const int colb = (w & 1) * 128, rowb = (w >> 1) * 64;
  const long rowbase = (long)blockIdx.x * 128;

  { // stage X: f32 -> bf16, row-swizzled (^((row&7)<<4))
    const float* src = node + rowbase * 256;
    #pragma unroll
    for (int it = 0; it < 16; ++it) {
      int lb = (it * 256 + tid) * 16;
      int dst = lb ^ (((lb >> 9) & 7) << 4);
      const float4* s4 = (const float4*)(src + (lb >> 1));
      float4 f0 = s4[0], f1 = s4[1];
      uint4 v = { pack2bf(f0.x, f0.y), pack2bf(f0.z, f0.w),
                  pack2bf(f1.x, f1.y), pack2bf(f1.z, f1.w) };
      *(uint4*)(sm + dst) = v;
    }
  }
  __syncthreads();

  f32x16 zero = {};
  f32x16 acc[4][2];
  #pragma unroll
  for (int a = 0; a < 4; ++a) { acc[a][0] = zero; acc[a][1] = zero; }

  for (int kk = 0; kk < 16; ++kk) {          // layer 1, K=256
    bf16x8 bf[2];
    #pragma unroll
    for (int r = 0; r < 2; ++r) {
      int xr = rowb + r * 32 + l31;
      int off = (xr << 9) + (kk << 5) + (h << 4);
      off ^= (xr & 7) << 4;
      bf[r] = as_bf16x8(*(const uint4*)(sm + off));
    }
    #pragma unroll
    for (int a = 0; a < 4; ++a) {
      int col = colb + a * 32 + l31;
      bf16x8 af = as_bf16x8(*(const uint4*)((const unsigned char*)w1p +
                    (kk << 13) + (col << 5) + (h << 4)));
      acc[a][0] = mfma16(af, bf[0], acc[a][0]);
      acc[a][1] = mfma16(af, bf[1], acc[a][1]);
    }
  }
  __syncthreads();

  // hidden = relu(acc + b1) -> sm (bf16, swizzled)
  #pragma unroll
  for (int a = 0; a < 4; ++a)
    #pragma unroll
    for (int r = 0; r < 2; ++r) {
      int xr = rowb + r * 32 + l31;
      #pragma unroll
      for (int g = 0; g < 4; ++g) {
        int col = colb + a * 32 + g * 8 + h * 4;
        float4 bb = *(const float4*)(b1 + col);
        float v0 = fmaxf(acc[a][r][4 * g + 0] + bb.x, 0.f);
        float v1 = fmaxf(acc[a][r][4 * g + 1] + bb.y, 0.f);
        float v2 = fmaxf(acc[a][r][4 * g + 2] + bb.z, 0.f);
        float v3 = fmaxf(acc[a][r][4 * g + 3] + bb.w, 0.f);
        int off = (xr << 9) + (col << 1);
        off ^= (xr & 7) << 4;
        *(uint2*)(sm + off) = pack4bf(v0, v1, v2, v3);
      }
    }
  __syncthreads();

  #pragma unroll
  for (int a = 0; a < 4; ++a) { acc[a][0] = zero; acc[a][1] = zero; }
  for (int kk = 0; kk < 16; ++kk) {          // layer 2, K=256
    bf16x8 bf[2];
    #pragma unroll
    for (int r = 0; r < 2; ++r) {
      int xr = rowb + r * 32 + l31;
      int off = (xr << 9) + (kk << 5) + (h << 4);
      off ^= (xr & 7) << 4;
      bf[r] = as_bf16x8(*(const uint4*)(sm + off));
    }
    #pragma unroll
    for (int a = 0; a < 4; ++a) {
      int col = colb + a * 32 + l31;
      bf16x8 af = as_bf16x8(*(const uint4*)((const unsigned char*)w2p +
                    (kk << 13) + (col << 5) + (h << 4)));
      acc[a][0] = mfma16(af, bf[0], acc[a][0]);
      acc[a][1] = mfma16(af, bf[1], acc[a][1]);
    }
  }

  // store proj (bf16, linear row-major)
  #pragma unroll
  for (int a = 0; a < 4; ++a)
    #pragma unroll
    for (int r = 0; r < 2; ++r) {
      long row = rowbase + rowb + r * 32 + l31;
      #pragma unroll
      for (int g = 0; g < 4; ++g) {
        int col = colb + a * 32 + g * 8 + h * 4;
        float4 bb = *(const float4*)(b2 + col);
        uint2 v = pack4bf(acc[a][r][4 * g + 0] + bb.x, acc[a][r][4 * g + 1] + bb.y,
                          acc[a][r][4 * g + 2] + bb.z, acc[a][r][4 * g + 3] + bb.w);
        *(uint2*)(proj + row * 256 + col) = v;
      }
    }
}

// ---------------------------------------------------------------------------
// atom head: h = relu(node@Wa1+ba1); logits = h@Wa2+ba2 (118, padded 128)
// + in-register log-softmax(118), CE and argmax-acc reductions.
// ---------------------------------------------------------------------------
__global__ __launch_bounds__(256, 2) void k_atom(
    const float* __restrict__ node,
    const unsigned short* __restrict__ w1p, const float* __restrict__ b1,
    const unsigned short* __restrict__ w2p, const float* __restrict__ b2,
    const int* __restrict__ tgt, float* __restrict__ accum)
{
  __shared__ __align__(16) unsigned char sm[65536];
  const int tid = threadIdx.x;
  const int lane = tid & 63;
  const int w = tid >> 6;
  const int l31 = lane & 31;
  const int h = lane >> 5;
  const int colb = (w & 1) * 128, rowb = (w >> 1) * 64;
  const long rowbase = (long)blockIdx.x * 128;

  {
    const float* src = node + rowbase * 256;
    #pragma unroll
    for (int it = 0; it < 16; ++it) {
      int lb = (it * 256 + tid) * 16;
      int dst = lb ^ (((lb >> 9) & 7) << 4);
      const float4* s4 = (const float4*)(src + (lb >> 1));
      float4 f0 = s4[0], f1 = s4[1];
      uint4 v = { pack2bf(f0.x, f0.y), pack2bf(f0.z, f0.w),
                  pack2bf(f1.x, f1.y), pack2bf(f1.z, f1.w) };
      *(uint4*)(sm + dst) = v;
    }
  }
  __syncthreads();

  f32x16 zero = {};
  f32x16 acc[4][2];
  #pragma unroll
  for (int a = 0; a < 4; ++a) { acc[a][0] = zero; acc[a][1] = zero; }

  for (int kk = 0; kk < 16; ++kk) {          // layer 1
    bf16x8 bf[2];
    #pragma unroll
    for (int r = 0; r < 2; ++r) {
      int xr = rowb + r * 32 + l31;
      int off = (xr << 9) + (kk << 5) + (h << 4);
      off ^= (xr & 7) << 4;
      bf[r] = as_bf16x8(*(const uint4*)(sm + off));
    }
    #pragma unroll
    for (int a = 0; a < 4; ++a) {
      int col = colb + a * 32 + l31;
      bf16x8 af = as_bf16x8(*(const uint4*)((const unsigned char*)w1p +
                    (kk << 13) + (col << 5) + (h << 4)));
      acc[a][0] = mfma16(af, bf[0], acc[a][0]);
      acc[a][1] = mfma16(af, bf[1], acc[a][1]);
    }
  }
  __syncthreads();

  #pragma unroll
  for (int a = 0; a < 4; ++a)
    #pragma unroll
    for (int r = 0; r < 2; ++r) {
      int xr = rowb + r * 32 + l31;
      #pragma unroll
      for (int g = 0; g < 4; ++g) {
        int col = colb + a * 32 + g * 8 + h * 4;
        float4 bb = *(const float4*)(b1 + col);
        float v0 = fmaxf(acc[a][r][4 * g + 0] + bb.x, 0.f);
        float v1 = fmaxf(acc[a][r][4 * g + 1] + bb.y, 0.f);
        float v2 = fmaxf(acc[a][r][4 * g + 2] + bb.z, 0.f);
        float v3 = fmaxf(acc[a][r][4 * g + 3] + bb.w, 0.f);
        int off = (xr << 9) + (col << 1);
        off ^= (xr & 7) << 4;
        *(uint2*)(sm + off) = pack4bf(v0, v1, v2, v3);
      }
    }
  __syncthreads();

  // layer 2: wave handles rows w*32..w*32+31, all 128 (padded) cols
  f32x16 a2[4];
  #pragma unroll
  for (int a = 0; a < 4; ++a) a2[a] = zero;
  const int xr2 = w * 32 + l31;
  for (int kk = 0; kk < 16; ++kk) {
    int off = (xr2 << 9) + (kk << 5) + (h << 4);
    off ^= (xr2 & 7) << 4;
    bf16x8 bf = as_bf16x8(*(const uint4*)(sm + off));
    #pragma unroll
    for (int a = 0; a < 4; ++a) {
      int col = a * 32 + l31;
      bf16x8 af = as_bf16x8(*(const uint4*)((const unsigned char*)w2p +
                    (kk << 12) + (col << 5) + (h << 4)));
      a2[a] = mfma16(af, bf, a2[a]);
    }
  }

  // epilogue: lane pair (l, l^32) jointly holds the 118 logits of row xr2
  long grow = rowbase + xr2;
  int t = tgt[grow];
  float mx = -3.0e38f; int am = 0;
  #pragma unroll
  for (int a = 0; a < 4; ++a)
    #pragma unroll
    for (int q = 0; q < 16; ++q) {
      int col = a * 32 + (q & 3) + 8 * (q >> 2) + 4 * h;
      if (col < 118) {
        float v = a2[a][q] + b2[col];
        a2[a][q] = v;
        if (v > mx) { mx = v; am = col; }   // ascending col -> first-index ties
      }
    }
  float omx = __shfl_xor(mx, 32); int oam = __shfl_xor(am, 32);
  if (omx > mx || (omx == mx && oam < am)) { mx = omx; am = oam; }
  float s = 0.f;
  #pragma unroll
  for (int a = 0; a < 4; ++a)
    #pragma unroll
    for (int q = 0; q < 16; ++q) {
      int col = a * 32 + (q & 3) + 8 * (q >> 2) + 4 * h;
      if (col < 118) s += __expf(a2[a][q] - mx);
    }
  s += __shfl_xor(s, 32);
  float vt = 0.f;
  #pragma unroll
  for (int a = 0; a < 4; ++a)
    #pragma unroll
    for (int q = 0; q < 16; ++q) {
      int col = a * 32 + (q & 3) + 8 * (q >> 2) + 4 * h;
      if (col < 118 && col == t) vt = a2[a][q];
    }
  vt += __shfl_xor(vt, 32);
  float ce = __logf(s) + mx - vt;
  float cc = (am == t) ? 1.f : 0.f;
  if (h) { ce = 0.f; cc = 0.f; }
  #pragma unroll
  for (int d = 1; d < 64; d <<= 1) { ce += __shfl_xor(ce, d); cc += __shfl_xor(cc, d); }
  if (lane == 0) { atomicAdd(accum + 2, ce); atomicAdd(accum + 3, cc); }
}

// ---------------------------------------------------------------------------
// bond head: one molecule per block. Stage proj[m] (64x256 bf16) in LDS;
// gather endpoints during B-fragment loads; layer1 K=512 MFMA; hidden in LDS;
// layer2 N=4 (padded 32) MFMA; softmax4 + CE/acc reductions.
// ---------------------------------------------------------------------------
__global__ __launch_bounds__(256, 2) void k_bond(
    const unsigned short* __restrict__ proj, const int* __restrict__ eidx,
    const int* __restrict__ tgt,
    const unsigned short* __restrict__ w1p, const float* __restrict__ b1,
    const unsigned short* __restrict__ w2p, const float* __restrict__ b2,
    float* __restrict__ accum)
{
  __shared__ __align__(16) unsigned char sm[65536]; // union: X[64][256] / hidden[128][256]
  const int tid = threadIdx.x;
  const int lane = tid & 63;
  const int w = tid >> 6;
  const int l31 = lane & 31;
  const int h = lane >> 5;
  const int colb = (w & 1) * 128, rowb = (w >> 1) * 64;
  const int m = blockIdx.x;

  { // stage proj[m] 32KB (bf16 -> bf16, row-swizzled)
    const unsigned char* pm = (const unsigned char*)(proj + (long)m * 16384);
    #pragma unroll
    for (int it = 0; it < 8; ++it) {
      int lb = (it * 256 + tid) * 16;
      int dst = lb ^ (((lb >> 9) & 7) << 4);
      *(uint4*)(sm + dst) = *(const uint4*)(pm + lb);
    }
  }
  int ea[2], eb[2];
  #pragma unroll
  for (int r = 0; r < 2; ++r) {
    int er = rowb + r * 32 + l31;
    ea[r] = eidx[m * 256 + er];        // start atom
    eb[r] = eidx[m * 256 + 128 + er];  // end atom
  }
  __syncthreads();

  f32x16 zero = {};
  f32x16 acc[4][2];
  #pragma unroll
  for (int a = 0; a < 4; ++a) { acc[a][0] = zero; acc[a][1] = zero; }

  for (int kk = 0; kk < 32; ++kk) {          // layer 1, K=512 (k<256: start, else end)
    bf16x8 bf[2];
    #pragma unroll
    for (int r = 0; r < 2; ++r) {
      int atom = (kk < 16) ? ea[r] : eb[r];
      int off = (atom << 9) + ((kk & 15) << 5) + (h << 4);
      off ^= (atom & 7) << 4;
      bf[r] = as_bf16x8(*(const uint4*)(sm + off));
    }
    #pragma unroll
    for (int a = 0; a < 4; ++a) {
      int col = colb + a * 32 + l31;
      bf16x8 af = as_bf16x8(*(const uint4*)((const unsigned char*)w1p +
                    (kk << 13) + (col << 5) + (h << 4)));
      acc[a][0] = mfma16(af, bf[0], acc[a][0]);
      acc[a][1] = mfma16(af, bf[1], acc[a][1]);
    }
  }
  __syncthreads();

  #pragma unroll
  for (int a = 0; a < 4; ++a)
    #pragma unroll
    for (int r = 0; r < 2; ++r) {
      int xr = rowb + r * 32 + l31;
      #pragma unroll
      for (int g = 0; g < 4; ++g) {
        int col = colb + a * 32 + g * 8 + h * 4;
        float4 bb = *(const float4*)(b1 + col);
        float v0 = fmaxf(acc[a][r][4 * g + 0] + bb.x, 0.f);
        float v1 = fmaxf(acc[a][r][4 * g + 1] + bb.y, 0.f);
        float v2 = fmaxf(acc[a][r][4 * g + 2] + bb.z, 0.f);
        float v3 = fmaxf(acc[a][r][4 * g + 3] + bb.w, 0.f);
        int off = (xr << 9) + (col << 1);
        off ^= (xr & 7) << 4;
        *(uint2*)(sm + off) = pack4bf(v0, v1, v2, v3);
      }
    }
  __syncthreads();

  // layer 2: wave handles edges w*32..w*32+31; cols 0..31 (4 real)
  f32x16 a2 = zero;
  const int er2 = w * 32 + l31;
  for (int kk = 0; kk < 16; ++kk) {
    int off = (er2 << 9) + (kk << 5) + (h << 4);
    off ^= (er2 & 7) << 4;
    bf16x8 bf = as_bf16x8(*(const uint4*)(sm + off));
    bf16x8 af = as_bf16x8(*(const uint4*)((const unsigned char*)w2p +
                  (kk << 10) + (l31 << 5) + (h << 4)));
    a2 = mfma16(af, bf, a2);
  }

  float ce = 0.f, cc = 0.f;
  if (h == 0) {   // regs 0..3 hold logits 0..3 for edge er2
    float l0 = a2[0] + b2[0], l1 = a2[1] + b2[1], l2 = a2[2] + b2[2], l3 = a2[3] + b2[3];
    int t = tgt[m * 128 + er2];
    int am = 0; float mx = l0;
    if (l1 > mx) { mx = l1; am = 1; }
    if (l2 > mx) { mx = l2; am = 2; }
    if (l3 > mx) { mx = l3; am = 3; }
    float s = __expf(l0 - mx) + __expf(l1 - mx) + __expf(l2 - mx) + __expf(l3 - mx);
    float lt = (t == 0) ? l0 : (t == 1) ? l1 : (t == 2) ? l2 : l3;
    ce = __logf(s) + mx - lt;
    cc = (am == t) ? 1.f : 0.f;
  }
  #pragma unroll
  for (int d = 1; d < 64; d <<= 1) { ce += __shfl_xor(ce, d); cc += __shfl_xor(cc, d); }
  if (lane == 0) { atomicAdd(accum + 0, ce); atomicAdd(accum + 1, cc); }
}

__global__ __launch_bounds__(64) void k_final(const float* __restrict__ accum,
                                              float* __restrict__ out)
{
  if (threadIdx.x == 0) {
    float bce = accum[0] / 262144.f;
    float bcc = accum[1] / 262144.f;
    float ace = accum[2] / 131072.f;
    float acc_ = accum[3] / 131072.f;
    out[0] = 0.5f * bce + 0.5f * ace;
    out[1] = bcc;
    out[2] = acc_;
  }
}

extern "C" void kernel_launch(void* const* d_in, const int* in_sizes, int n_in,
                              void* d_out, int out_size, void* d_ws, size_t ws_size,
                              hipStream_t stream)
{
  const float* node = (const float*)d_in[0];
  const int* eidx   = (const int*)d_in[1];
  const int* btt    = (const int*)d_in[2];
  const int* att    = (const int*)d_in[3];
  const float* Wp1 = (const float*)d_in[4];
  const float* bp1 = (const float*)d_in[5];
  const float* Wp2 = (const float*)d_in[6];
  const float* bp2 = (const float*)d_in[7];
  const float* Wb1 = (const float*)d_in[8];
  const float* bb1 = (const float*)d_in[9];
  const float* Wb2 = (const float*)d_in[10];
  const float* bb2 = (const float*)d_in[11];
  const float* Wa1 = (const float*)d_in[12];
  const float* ba1 = (const float*)d_in[13];
  const float* Wa2 = (const float*)d_in[14];
  const float* ba2 = (const float*)d_in[15];

  char* ws = (char*)d_ws;
  float* accum = (float*)ws;
  unsigned short* dp1 = (unsigned short*)(ws + 256);
  unsigned short* dp2 = (unsigned short*)(ws + 256 + 131072);
  unsigned short* da1 = (unsigned short*)(ws + 256 + 262144);
  unsigned short* db1 = (unsigned short*)(ws + 256 + 393216);   // 256 KB
  unsigned short* da2 = (unsigned short*)(ws + 256 + 655360);   // 64 KB
  unsigned short* db2 = (unsigned short*)(ws + 256 + 720896);   // 16 KB
  unsigned short* projp = (unsigned short*)(ws + (1 << 20));    // 64 MB

  k_pack<<<1440, 256, 0, stream>>>(Wp1, Wp2, Wa1, Wb1, Wa2, Wb2,
                                   dp1, dp2, da1, db1, da2, db2, accum);
  k_proj<<<1024, 256, 0, stream>>>(node, dp1, bp1, dp2, bp2, projp);
  k_atom<<<1024, 256, 0, stream>>>(node, da1, ba1, da2, ba2, att, accum);
  k_bond<<<2048, 256, 0, stream>>>(projp, eidx, btt, db1, bb1, db2, bb2, accum);
  k_final<<<1, 64, 0, stream>>>(accum, (float*)d_out);
}

// Round 2
// 424.554 us; speedup vs baseline: 1.3948x; 1.3948x over previous
//
#include <hip/hip_runtime.h>
#include <hip/hip_bf16.h>

// M=2048, A=64, E=128, H=256, bond types=4, atom types=118
typedef __bf16 bf16x8 __attribute__((ext_vector_type(8)));
typedef float f32x16 __attribute__((ext_vector_type(16)));

__device__ inline unsigned short f2bf(float f) {
  __hip_bfloat16 h = __float2bfloat16(f);
  return *reinterpret_cast<unsigned short*>(&h);
}
__device__ inline unsigned pack2bf(float a, float b) {
  return (unsigned)f2bf(a) | ((unsigned)f2bf(b) << 16);
}
__device__ inline uint2 pack4bf(float a, float b, float c, float d) {
  uint2 r; r.x = pack2bf(a, b); r.y = pack2bf(c, d); return r;
}
__device__ inline bf16x8 as_bf16x8(uint4 v) { return __builtin_bit_cast(bf16x8, v); }
__device__ inline float bitf(unsigned u) { return __builtin_bit_cast(float, u); }
__device__ inline f32x16 mfma16(bf16x8 a, bf16x8 b, f32x16 c) {
  return __builtin_amdgcn_mfma_f32_32x32x16_bf16(a, b, c, 0, 0, 0);
}

// ---------------------------------------------------------------------------
// Pack Wp1 / Wa1 / Wa2 to bf16 fragment layout: ushort[(kk*N + n)*16 + dk],
// value = W[kk*16+dk][n], zero-pad n >= Nreal.
// blocks: [0,256) Wp1  [256,512) Wa1  [512,640) Wa2 (N=128, Nreal=118)
// ---------------------------------------------------------------------------
__global__ __launch_bounds__(256) void k_pack(
    const float* __restrict__ wp1, const float* __restrict__ wa1,
    const float* __restrict__ wa2,
    unsigned short* __restrict__ dp1, unsigned short* __restrict__ da1,
    unsigned short* __restrict__ da2, float* __restrict__ accum)
{
  int b = blockIdx.x, tid = threadIdx.x;
  if (b == 0 && tid < 8) accum[tid] = 0.f;
  const float* src; unsigned short* dst; int e, logN, Nreal;
  if (b < 256)       { src = wp1; dst = dp1; e = b * 256 + tid;          logN = 8; Nreal = 256; }
  else if (b < 512)  { src = wa1; dst = da1; e = (b - 256) * 256 + tid;  logN = 8; Nreal = 256; }
  else               { src = wa2; dst = da2; e = (b - 512) * 256 + tid;  logN = 7; Nreal = 118; }
  int dk = e & 15;
  int rest = e >> 4;
  int n = rest & ((1 << logN) - 1);
  int kk = rest >> logN;
  int k = kk * 16 + dk;
  float v = (n < Nreal) ? src[k * Nreal + n] : 0.f;
  dst[e] = f2bf(v);
}

// ---------------------------------------------------------------------------
// Fold: Wct = Wp2 @ Wb1[0:256,:], Wcb = Wp2 @ Wb1[256:512,:]  (packed bf16)
//       bias_e = bp2 @ Wb1t + bp2 @ Wb1b + bb1  (f32[256])
// blocks [0,256): Wct row k   [256,512): Wcb row k   512: bias
// ---------------------------------------------------------------------------
__global__ __launch_bounds__(256) void k_fold(
    const float* __restrict__ wp2, const float* __restrict__ wb1,
    const float* __restrict__ bp2, const float* __restrict__ bb1,
    unsigned short* __restrict__ dct, unsigned short* __restrict__ dcb,
    float* __restrict__ bias_e)
{
  int b = blockIdx.x, n = threadIdx.x;
  if (b < 512) {
    int k = b & 255;
    int off = (b < 256) ? 0 : 256;
    float s = 0.f;
    for (int t = 0; t < 256; ++t)
      s += wp2[k * 256 + t] * wb1[(t + off) * 256 + n];
    unsigned short* dst = (b < 256) ? dct : dcb;
    dst[((k >> 4) * 256 + n) * 16 + (k & 15)] = f2bf(s);
  } else {
    float s = bb1[n];
    for (int t = 0; t < 256; ++t)
      s += bp2[t] * (wb1[t * 256 + n] + wb1[(256 + t) * 256 + n]);
    bias_e[n] = s;
  }
}

// ---------------------------------------------------------------------------
// Fused bond kernel: one molecule (64 atoms, 128 edges) per block, 4 waves.
// Wave (rb=w>>1, cb=w&1): rows rb*32..+31, cols cb*128..+127 of each GEMM.
//   bufA: X(bf16,swz) -> h1 (in-place) -> he (in-place)
//   bufB: hs
// Edge phase: thread t -> edge t>>1, col-half t&1; gather+relu+N=4 dot.
// ---------------------------------------------------------------------------
__global__ __launch_bounds__(256, 2) void k_bond(
    const float* __restrict__ node, const int* __restrict__ eidx,
    const int* __restrict__ tgt,
    const unsigned short* __restrict__ wp1p, const float* __restrict__ bp1,
    const unsigned short* __restrict__ wctp, const unsigned short* __restrict__ wcbp,
    const float* __restrict__ bias_e, const float* __restrict__ wb2,
    const float* __restrict__ bb2, float* __restrict__ accum)
{
  __shared__ __align__(16) unsigned char bufA[32768];
  __shared__ __align__(16) unsigned char bufB[32768];
  __shared__ float s_bias[256];
  __shared__ float4 s_wb2[256];
  const int tid = threadIdx.x;
  const int lane = tid & 63;
  const int w = tid >> 6;
  const int l31 = lane & 31;
  const int h = lane >> 5;
  const int rb = w >> 1, cb = w & 1;
  const int m = blockIdx.x;

  { // stage X: 64x256 f32 -> bf16, row-swizzled
    const float* src = node + (long)m * 16384;
    #pragma unroll
    for (int it = 0; it < 8; ++it) {
      int lb = (it * 256 + tid) * 16;
      int dst = lb ^ (((lb >> 9) & 7) << 4);
      const float4* s4 = (const float4*)(src + (lb >> 1));
      float4 f0 = s4[0], f1 = s4[1];
      uint4 v = { pack2bf(f0.x, f0.y), pack2bf(f0.z, f0.w),
                  pack2bf(f1.x, f1.y), pack2bf(f1.z, f1.w) };
      *(uint4*)(bufA + dst) = v;
    }
    s_bias[tid] = bias_e[tid];
    s_wb2[tid] = ((const float4*)wb2)[tid];
  }
  const int es = eidx[m * 256 + (tid >> 1)];
  const int ed = eidx[m * 256 + 128 + (tid >> 1)];
  const int etg = tgt[m * 128 + (tid >> 1)];
  const float q0 = bb2[0], q1 = bb2[1], q2 = bb2[2], q3 = bb2[3];
  __syncthreads();                               // b1: staging visible

  const int xr = rb * 32 + l31;
  const int xswz = (xr & 7) << 4;
  auto xaddr = [&](int kk) { return ((xr << 9) + (kk << 5) + (h << 4)) ^ xswz; };

  f32x16 zero = {};
  f32x16 acc[4];

  auto gemm = [&](const unsigned char* xb, const unsigned short* wp) {
    const unsigned char* wbase = (const unsigned char*)wp +
        ((cb * 128 + l31) << 5) + (h << 4);
    #pragma unroll
    for (int a = 0; a < 4; ++a) acc[a] = zero;
    bf16x8 bv0 = *(const bf16x8*)(xb + xaddr(0));
    uint4 a0[4], a1[4];
    #pragma unroll
    for (int a = 0; a < 4; ++a) a0[a] = *(const uint4*)(wbase + (a << 10));
    #pragma unroll
    for (int kk = 0; kk < 16; kk += 2) {
      bf16x8 bv1 = *(const bf16x8*)(xb + xaddr(kk + 1));
      #pragma unroll
      for (int a = 0; a < 4; ++a)
        a1[a] = *(const uint4*)(wbase + ((kk + 1) << 13) + (a << 10));
      #pragma unroll
      for (int a = 0; a < 4; ++a) acc[a] = mfma16(as_bf16x8(a0[a]), bv0, acc[a]);
      if (kk + 2 < 16) {
        bv0 = *(const bf16x8*)(xb + xaddr(kk + 2));
        #pragma unroll
        for (int a = 0; a < 4; ++a)
          a0[a] = *(const uint4*)(wbase + ((kk + 2) << 13) + (a << 10));
      }
      #pragma unroll
      for (int a = 0; a < 4; ++a) acc[a] = mfma16(as_bf16x8(a1[a]), bv1, acc[a]);
    }
  };

  auto writeback_relu = [&](unsigned char* db, const float* bias) {
    #pragma unroll
    for (int a = 0; a < 4; ++a)
      #pragma unroll
      for (int g = 0; g < 4; ++g) {
        int col = cb * 128 + a * 32 + g * 8 + h * 4;
        float4 bb = *(const float4*)(bias + col);
        float v0 = fmaxf(acc[a][4 * g + 0] + bb.x, 0.f);
        float v1 = fmaxf(acc[a][4 * g + 1] + bb.y, 0.f);
        float v2 = fmaxf(acc[a][4 * g + 2] + bb.z, 0.f);
        float v3 = fmaxf(acc[a][4 * g + 3] + bb.w, 0.f);
        int off = ((xr << 9) + (col << 1)) ^ xswz;
        *(uint2*)(db + off) = pack4bf(v0, v1, v2, v3);
      }
  };
  auto writeback_raw = [&](unsigned char* db) {
    #pragma unroll
    for (int a = 0; a < 4; ++a)
      #pragma unroll
      for (int g = 0; g < 4; ++g) {
        int col = cb * 128 + a * 32 + g * 8 + h * 4;
        int off = ((xr << 9) + (col << 1)) ^ xswz;
        *(uint2*)(db + off) = pack4bf(acc[a][4 * g + 0], acc[a][4 * g + 1],
                                      acc[a][4 * g + 2], acc[a][4 * g + 3]);
      }
  };

  gemm(bufA, wp1p);        // h1 pre-act
  __syncthreads();         // b2: all X reads done
  writeback_relu(bufA, bp1);
  __syncthreads();         // b3: h1 visible

  gemm(bufA, wctp);        // hs
  writeback_raw(bufB);
  gemm(bufA, wcbp);        // he (acc in regs)
  __syncthreads();         // b4: all h1 reads + hs writes done
  writeback_raw(bufA);     // he over h1
  __syncthreads();         // b5: hs/he visible

  // ---- edge phase ----
  {
    const int hf = tid & 1;
    float lg0 = 0.f, lg1 = 0.f, lg2 = 0.f, lg3 = 0.f;
    #pragma unroll
    for (int j = 0; j < 16; ++j) {
      int c0 = hf * 128 + j * 8;
      int offS = ((es << 9) + (c0 << 1)) ^ ((es & 7) << 4);
      int offD = ((ed << 9) + (c0 << 1)) ^ ((ed & 7) << 4);
      uint4 us = *(const uint4*)(bufB + offS);
      uint4 ud = *(const uint4*)(bufA + offD);
      const unsigned* pu = (const unsigned*)&us;
      const unsigned* pv = (const unsigned*)&ud;
      #pragma unroll
      for (int q = 0; q < 4; ++q) {
        unsigned ua = pu[q], ub = pv[q];
        int c = c0 + 2 * q;
        float hlo = bitf(ua << 16) + bitf(ub << 16) + s_bias[c];
        float hhi = bitf(ua & 0xffff0000u) + bitf(ub & 0xffff0000u) + s_bias[c + 1];
        hlo = fmaxf(hlo, 0.f); hhi = fmaxf(hhi, 0.f);
        float4 w0 = s_wb2[c], w1 = s_wb2[c + 1];
        lg0 = fmaf(hlo, w0.x, fmaf(hhi, w1.x, lg0));
        lg1 = fmaf(hlo, w0.y, fmaf(hhi, w1.y, lg1));
        lg2 = fmaf(hlo, w0.z, fmaf(hhi, w1.z, lg2));
        lg3 = fmaf(hlo, w0.w, fmaf(hhi, w1.w, lg3));
      }
    }
    lg0 += __shfl_xor(lg0, 1); lg1 += __shfl_xor(lg1, 1);
    lg2 += __shfl_xor(lg2, 1); lg3 += __shfl_xor(lg3, 1);
    float ce = 0.f, cc = 0.f;
    if (hf == 0) {
      float l0 = lg0 + q0, l1 = lg1 + q1, l2 = lg2 + q2, l3 = lg3 + q3;
      int t = etg;
      int am = 0; float mx = l0;
      if (l1 > mx) { mx = l1; am = 1; }
      if (l2 > mx) { mx = l2; am = 2; }
      if (l3 > mx) { mx = l3; am = 3; }
      float s = __expf(l0 - mx) + __expf(l1 - mx) + __expf(l2 - mx) + __expf(l3 - mx);
      float lt = (t == 0) ? l0 : (t == 1) ? l1 : (t == 2) ? l2 : l3;
      ce = __logf(s) + mx - lt;
      cc = (am == t) ? 1.f : 0.f;
    }
    #pragma unroll
    for (int d = 1; d < 64; d <<= 1) { ce += __shfl_xor(ce, d); cc += __shfl_xor(cc, d); }
    if (lane == 0) { atomicAdd(accum + 0, ce); atomicAdd(accum + 1, cc); }
  }
}

// ---------------------------------------------------------------------------
// Atom head: 128 rows/block, 4 waves, each wave 32 rows x 256 cols.
// ha = relu(X@Wa1+ba1) in-place in LDS; logits = ha@Wa2 (118 pad 128);
// per-lane-pair log-softmax epilogue. Only one barrier (after staging).
// ---------------------------------------------------------------------------
__global__ __launch_bounds__(256, 2) void k_atom(
    const float* __restrict__ node,
    const unsigned short* __restrict__ w1p, const float* __restrict__ b1,
    const unsigned short* __restrict__ w2p, const float* __restrict__ b2,
    const int* __restrict__ tgt, float* __restrict__ accum)
{
  __shared__ __align__(16) unsigned char sm[65536];
  const int tid = threadIdx.x;
  const int lane = tid & 63;
  const int w = tid >> 6;
  const int l31 = lane & 31;
  const int h = lane >> 5;
  const long rowbase = (long)blockIdx.x * 128;

  {
    const float* src = node + rowbase * 256;
    #pragma unroll
    for (int it = 0; it < 16; ++it) {
      int lb = (it * 256 + tid) * 16;
      int dst = lb ^ (((lb >> 9) & 7) << 4);
      const float4* s4 = (const float4*)(src + (lb >> 1));
      float4 f0 = s4[0], f1 = s4[1];
      uint4 v = { pack2bf(f0.x, f0.y), pack2bf(f0.z, f0.w),
                  pack2bf(f1.x, f1.y), pack2bf(f1.z, f1.w) };
      *(uint4*)(sm + dst) = v;
    }
  }
  __syncthreads();   // only barrier: after this everything is wave-local rows

  const int xr = w * 32 + l31;
  const int xswz = (xr & 7) << 4;
  auto xaddr = [&](int kk) { return ((xr << 9) + (kk << 5) + (h << 4)) ^ xswz; };

  f32x16 zero = {};
  // ---- layer 1: 8 col-tiles, manual 1-deep prefetch ----
  f32x16 acc8[8];
  {
    const unsigned char* wbase = (const unsigned char*)w1p + (l31 << 5) + (h << 4);
    #pragma unroll
    for (int a = 0; a < 8; ++a) acc8[a] = zero;
    bf16x8 bv0 = *(const bf16x8*)(sm + xaddr(0));
    uint4 a0[8], a1[8];
    #pragma unroll
    for (int a = 0; a < 8; ++a) a0[a] = *(const uint4*)(wbase + (a << 10));
    #pragma unroll
    for (int kk = 0; kk < 16; kk += 2) {
      bf16x8 bv1 = *(const bf16x8*)(sm + xaddr(kk + 1));
      #pragma unroll
      for (int a = 0; a < 8; ++a)
        a1[a] = *(const uint4*)(wbase + ((kk + 1) << 13) + (a << 10));
      #pragma unroll
      for (int a = 0; a < 8; ++a) acc8[a] = mfma16(as_bf16x8(a0[a]), bv0, acc8[a]);
      if (kk + 2 < 16) {
        bv0 = *(const bf16x8*)(sm + xaddr(kk + 2));
        #pragma unroll
        for (int a = 0; a < 8; ++a)
          a0[a] = *(const uint4*)(wbase + ((kk + 2) << 13) + (a << 10));
      }
      #pragma unroll
      for (int a = 0; a < 8; ++a) acc8[a] = mfma16(as_bf16x8(a1[a]), bv1, acc8[a]);
    }
  }
  // write relu(ha + b1) in-place over X (own rows only)
  #pragma unroll
  for (int a = 0; a < 8; ++a)
    #pragma unroll
    for (int g = 0; g < 4; ++g) {
      int col = a * 32 + g * 8 + h * 4;
      float4 bb = *(const float4*)(b1 + col);
      float v0 = fmaxf(acc8[a][4 * g + 0] + bb.x, 0.f);
      float v1 = fmaxf(acc8[a][4 * g + 1] + bb.y, 0.f);
      float v2 = fmaxf(acc8[a][4 * g + 2] + bb.z, 0.f);
      float v3 = fmaxf(acc8[a][4 * g + 3] + bb.w, 0.f);
      int off = ((xr << 9) + (col << 1)) ^ xswz;
      *(uint2*)(sm + off) = pack4bf(v0, v1, v2, v3);
    }

  // ---- layer 2: N=128 (4 col-tiles), reads own rows ----
  f32x16 a2[4];
  #pragma unroll
  for (int a = 0; a < 4; ++a) a2[a] = zero;
  {
    const unsigned char* wbase = (const unsigned char*)w2p + (l31 << 5) + (h << 4);
    #pragma unroll
    for (int kk = 0; kk < 16; ++kk) {
      bf16x8 bv = *(const bf16x8*)(sm + xaddr(kk));
      #pragma unroll
      for (int a = 0; a < 4; ++a)
        a2[a] = mfma16(as_bf16x8(*(const uint4*)(wbase + (kk << 12) + (a << 10))),
                       bv, a2[a]);
    }
  }

  // ---- epilogue: lane pair (l, l^32) holds the 118 logits of row xr ----
  long grow = rowbase + xr;
  int t = tgt[grow];
  float mx = -3.0e38f; int am = 0;
  #pragma unroll
  for (int a = 0; a < 4; ++a)
    #pragma unroll
    for (int q = 0; q < 16; ++q) {
      int col = a * 32 + (q & 3) + 8 * (q >> 2) + 4 * h;
      if (col < 118) {
        float v = a2[a][q] + b2[col];
        a2[a][q] = v;
        if (v > mx) { mx = v; am = col; }
      }
    }
  float omx = __shfl_xor(mx, 32); int oam = __shfl_xor(am, 32);
  if (omx > mx || (omx == mx && oam < am)) { mx = omx; am = oam; }
  float s = 0.f;
  #pragma unroll
  for (int a = 0; a < 4; ++a)
    #pragma unroll
    for (int q = 0; q < 16; ++q) {
      int col = a * 32 + (q & 3) + 8 * (q >> 2) + 4 * h;
      if (col < 118) s += __expf(a2[a][q] - mx);
    }
  s += __shfl_xor(s, 32);
  float vt = 0.f;
  #pragma unroll
  for (int a = 0; a < 4; ++a)
    #pragma unroll
    for (int q = 0; q < 16; ++q) {
      int col = a * 32 + (q & 3) + 8 * (q >> 2) + 4 * h;
      if (col < 118 && col == t) vt = a2[a][q];
    }
  vt += __shfl_xor(vt, 32);
  float ce = __logf(s) + mx - vt;
  float cc = (am == t) ? 1.f : 0.f;
  if (h) { ce = 0.f; cc = 0.f; }
  #pragma unroll
  for (int d = 1; d < 64; d <<= 1) { ce += __shfl_xor(ce, d); cc += __shfl_xor(cc, d); }
  if (lane == 0) { atomicAdd(accum + 2, ce); atomicAdd(accum + 3, cc); }
}

__global__ __launch_bounds__(64) void k_final(const float* __restrict__ accum,
                                              float* __restrict__ out)
{
  if (threadIdx.x == 0) {
    float bce = accum[0] / 262144.f;
    float bcc = accum[1] / 262144.f;
    float ace = accum[2] / 131072.f;
    float acc_ = accum[3] / 131072.f;
    out[0] = 0.5f * bce + 0.5f * ace;
    out[1] = bcc;
    out[2] = acc_;
  }
}

extern "C" void kernel_launch(void* const* d_in, const int* in_sizes, int n_in,
                              void* d_out, int out_size, void* d_ws, size_t ws_size,
                              hipStream_t stream)
{
  const float* node = (const float*)d_in[0];
  const int* eidx   = (const int*)d_in[1];
  const int* btt    = (const int*)d_in[2];
  const int* att    = (const int*)d_in[3];
  const float* Wp1 = (const float*)d_in[4];
  const float* bp1 = (const float*)d_in[5];
  const float* Wp2 = (const float*)d_in[6];
  const float* bp2 = (const float*)d_in[7];
  const float* Wb1 = (const float*)d_in[8];
  const float* bb1 = (const float*)d_in[9];
  const float* Wb2 = (const float*)d_in[10];
  const float* bb2 = (const float*)d_in[11];
  const float* Wa1 = (const float*)d_in[12];
  const float* ba1 = (const float*)d_in[13];
  const float* Wa2 = (const float*)d_in[14];
  const float* ba2 = (const float*)d_in[15];

  char* ws = (char*)d_ws;
  float* accum = (float*)ws;
  unsigned short* dp1 = (unsigned short*)(ws + 256);
  unsigned short* da1 = (unsigned short*)(ws + 131328);
  unsigned short* da2 = (unsigned short*)(ws + 262400);
  unsigned short* dct = (unsigned short*)(ws + 327936);
  unsigned short* dcb = (unsigned short*)(ws + 459008);
  float* bias_e       = (float*)(ws + 590080);

  k_pack<<<640, 256, 0, stream>>>(Wp1, Wa1, Wa2, dp1, da1, da2, accum);
  k_fold<<<513, 256, 0, stream>>>(Wp2, Wb1, bp2, bb1, dct, dcb, bias_e);
  k_atom<<<1024, 256, 0, stream>>>(node, da1, ba1, da2, ba2, att, accum);
  k_bond<<<2048, 256, 0, stream>>>(node, eidx, btt, dp1, bp1, dct, dcb,
                                   bias_e, Wb2, bb2, accum);
  k_final<<<1, 64, 0, stream>>>(accum, (float*)d_out);
}

// Round 3
// 235.401 us; speedup vs baseline: 2.5156x; 1.8035x over previous
//
#include <hip/hip_runtime.h>
#include <hip/hip_bf16.h>

// M=2048, A=64, E=128, H=256, bond types=4, atom types=118
typedef __bf16 bf16x8 __attribute__((ext_vector_type(8)));
typedef float f32x16 __attribute__((ext_vector_type(16)));

__device__ inline unsigned short f2bf(float f) {
  __hip_bfloat16 h = __float2bfloat16(f);
  return *reinterpret_cast<unsigned short*>(&h);
}
__device__ inline unsigned pack2bf(float a, float b) {
  return (unsigned)f2bf(a) | ((unsigned)f2bf(b) << 16);
}
__device__ inline uint2 pack4bf(float a, float b, float c, float d) {
  uint2 r; r.x = pack2bf(a, b); r.y = pack2bf(c, d); return r;
}
__device__ inline bf16x8 as_bf16x8(uint4 v) { return __builtin_bit_cast(bf16x8, v); }
__device__ inline float bitf(unsigned u) { return __builtin_bit_cast(float, u); }
__device__ inline f32x16 mfma16(bf16x8 a, bf16x8 b, f32x16 c) {
  return __builtin_amdgcn_mfma_f32_32x32x16_bf16(a, b, c, 0, 0, 0);
}

// byte addr of X/h LDS element (row xr, k-chunk kk, half h), XOR row-swizzle
#define XADDR(kk) ((((xr) << 9) + ((kk) << 5) + (h << 4)) ^ xswz)

// 4-col-tile GEMM over K=256, ping-pong weight prefetch, named regs only.
// Writes acc0..acc3 (declared in caller). WB_: per-lane N-stride for tiles.
#define GEMM4(XB, WPTR, CBASE)                                                 \
  {                                                                            \
    const unsigned char* wb_ = (const unsigned char*)(WPTR) +                  \
                               (((CBASE) + l31) << 5) + (h << 4);              \
    acc0 = zero; acc1 = zero; acc2 = zero; acc3 = zero;                        \
    bf16x8 bva = *(const bf16x8*)((XB) + XADDR(0));                            \
    uint4 p0 = *(const uint4*)(wb_ + 0);                                       \
    uint4 p1 = *(const uint4*)(wb_ + 1024);                                    \
    uint4 p2 = *(const uint4*)(wb_ + 2048);                                    \
    uint4 p3 = *(const uint4*)(wb_ + 3072);                                    \
    _Pragma("unroll")                                                          \
    for (int kk = 0; kk < 16; kk += 2) {                                       \
      bf16x8 bvb = *(const bf16x8*)((XB) + XADDR(kk + 1));                     \
      uint4 q0 = *(const uint4*)(wb_ + ((kk + 1) << 13) + 0);                  \
      uint4 q1 = *(const uint4*)(wb_ + ((kk + 1) << 13) + 1024);               \
      uint4 q2 = *(const uint4*)(wb_ + ((kk + 1) << 13) + 2048);               \
      uint4 q3 = *(const uint4*)(wb_ + ((kk + 1) << 13) + 3072);               \
      acc0 = mfma16(as_bf16x8(p0), bva, acc0);                                 \
      acc1 = mfma16(as_bf16x8(p1), bva, acc1);                                 \
      acc2 = mfma16(as_bf16x8(p2), bva, acc2);                                 \
      acc3 = mfma16(as_bf16x8(p3), bva, acc3);                                 \
      if (kk + 2 < 16) {                                                       \
        bva = *(const bf16x8*)((XB) + XADDR(kk + 2));                          \
        p0 = *(const uint4*)(wb_ + ((kk + 2) << 13) + 0);                      \
        p1 = *(const uint4*)(wb_ + ((kk + 2) << 13) + 1024);                   \
        p2 = *(const uint4*)(wb_ + ((kk + 2) << 13) + 2048);                   \
        p3 = *(const uint4*)(wb_ + ((kk + 2) << 13) + 3072);                   \
      }                                                                        \
      acc0 = mfma16(as_bf16x8(q0), bvb, acc0);                                 \
      acc1 = mfma16(as_bf16x8(q1), bvb, acc1);                                 \
      acc2 = mfma16(as_bf16x8(q2), bvb, acc2);                                 \
      acc3 = mfma16(as_bf16x8(q3), bvb, acc3);                                 \
    }                                                                          \
  }

// write one 32-col tile of a named acc to LDS (bf16, swizzled), optional relu
#define WB_TILE(DB, ACC, A, CBASE, BIASPTR, RELU)                              \
  _Pragma("unroll")                                                            \
  for (int g = 0; g < 4; ++g) {                                                \
    int col = (CBASE) + (A) * 32 + g * 8 + h * 4;                              \
    float4 bb = *(const float4*)((BIASPTR) + col);                             \
    float v0 = ACC[4 * g + 0] + bb.x;                                          \
    float v1 = ACC[4 * g + 1] + bb.y;                                          \
    float v2 = ACC[4 * g + 2] + bb.z;                                          \
    float v3 = ACC[4 * g + 3] + bb.w;                                          \
    if (RELU) { v0 = fmaxf(v0, 0.f); v1 = fmaxf(v1, 0.f);                      \
                v2 = fmaxf(v2, 0.f); v3 = fmaxf(v3, 0.f); }                    \
    int off = (((xr) << 9) + (col << 1)) ^ xswz;                               \
    *(uint2*)((DB) + off) = pack4bf(v0, v1, v2, v3);                           \
  }

#define WB_TILE_RAW(DB, ACC, A, CBASE)                                         \
  _Pragma("unroll")                                                            \
  for (int g = 0; g < 4; ++g) {                                                \
    int col = (CBASE) + (A) * 32 + g * 8 + h * 4;                              \
    int off = (((xr) << 9) + (col << 1)) ^ xswz;                               \
    *(uint2*)((DB) + off) = pack4bf(ACC[4 * g + 0], ACC[4 * g + 1],            \
                                    ACC[4 * g + 2], ACC[4 * g + 3]);           \
  }

// ---------------------------------------------------------------------------
// Pack Wp1 / Wa1 / Wa2 to bf16 fragment layout: ushort[(kk*N + n)*16 + dk],
// value = W[kk*16+dk][n], zero-pad n >= Nreal.
// ---------------------------------------------------------------------------
__global__ __launch_bounds__(256) void k_pack(
    const float* __restrict__ wp1, const float* __restrict__ wa1,
    const float* __restrict__ wa2,
    unsigned short* __restrict__ dp1, unsigned short* __restrict__ da1,
    unsigned short* __restrict__ da2, float* __restrict__ accum)
{
  int b = blockIdx.x, tid = threadIdx.x;
  if (b == 0 && tid < 8) accum[tid] = 0.f;
  const float* src; unsigned short* dst; int e, logN, Nreal;
  if (b < 256)       { src = wp1; dst = dp1; e = b * 256 + tid;          logN = 8; Nreal = 256; }
  else if (b < 512)  { src = wa1; dst = da1; e = (b - 256) * 256 + tid;  logN = 8; Nreal = 256; }
  else               { src = wa2; dst = da2; e = (b - 512) * 256 + tid;  logN = 7; Nreal = 118; }
  int dk = e & 15;
  int rest = e >> 4;
  int n = rest & ((1 << logN) - 1);
  int kk = rest >> logN;
  int k = kk * 16 + dk;
  float v = (n < Nreal) ? src[k * Nreal + n] : 0.f;
  dst[e] = f2bf(v);
}

// ---------------------------------------------------------------------------
// Fold: Wct = Wp2 @ Wb1[0:256,:], Wcb = Wp2 @ Wb1[256:512,:]  (packed bf16)
//       bias_e = bp2 @ (Wb1t+Wb1b) + bb1
// ---------------------------------------------------------------------------
__global__ __launch_bounds__(256) void k_fold(
    const float* __restrict__ wp2, const float* __restrict__ wb1,
    const float* __restrict__ bp2, const float* __restrict__ bb1,
    unsigned short* __restrict__ dct, unsigned short* __restrict__ dcb,
    float* __restrict__ bias_e)
{
  int b = blockIdx.x, n = threadIdx.x;
  if (b < 512) {
    int k = b & 255;
    int off = (b < 256) ? 0 : 256;
    float s = 0.f;
    for (int t = 0; t < 256; ++t)
      s += wp2[k * 256 + t] * wb1[(t + off) * 256 + n];
    unsigned short* dst = (b < 256) ? dct : dcb;
    dst[((k >> 4) * 256 + n) * 16 + (k & 15)] = f2bf(s);
  } else {
    float s = bb1[n];
    for (int t = 0; t < 256; ++t)
      s += bp2[t] * (wb1[t * 256 + n] + wb1[(256 + t) * 256 + n]);
    bias_e[n] = s;
  }
}

// ---------------------------------------------------------------------------
// Fused bond kernel: one molecule (64 atoms, 128 edges) per block, 4 waves.
// bufA: X(bf16,swz) -> h1 (in-place) -> he (in-place);  bufB: hs.
// ---------------------------------------------------------------------------
__global__ __launch_bounds__(256, 2) void k_bond(
    const float* __restrict__ node, const int* __restrict__ eidx,
    const int* __restrict__ tgt,
    const unsigned short* __restrict__ wp1p, const float* __restrict__ bp1,
    const unsigned short* __restrict__ wctp, const unsigned short* __restrict__ wcbp,
    const float* __restrict__ bias_e, const float* __restrict__ wb2,
    const float* __restrict__ bb2, float* __restrict__ accum)
{
  __shared__ __align__(16) unsigned char bufA[32768];
  __shared__ __align__(16) unsigned char bufB[32768];
  __shared__ float s_bias[256];
  __shared__ float4 s_wb2[256];
  __shared__ float s_red[8];
  const int tid = threadIdx.x;
  const int lane = tid & 63;
  const int w = tid >> 6;
  const int l31 = lane & 31;
  const int h = lane >> 5;
  const int rb = w >> 1, cb = w & 1;
  const int m = blockIdx.x;

  { // stage X: 64x256 f32 -> bf16, row-swizzled
    const float* src = node + (long)m * 16384;
    #pragma unroll
    for (int it = 0; it < 8; ++it) {
      int lb = (it * 256 + tid) * 16;
      int dst = lb ^ (((lb >> 9) & 7) << 4);
      const float4* s4 = (const float4*)(src + (lb >> 1));
      float4 f0 = s4[0], f1 = s4[1];
      uint4 v = { pack2bf(f0.x, f0.y), pack2bf(f0.z, f0.w),
                  pack2bf(f1.x, f1.y), pack2bf(f1.z, f1.w) };
      *(uint4*)(bufA + dst) = v;
    }
    s_bias[tid] = bias_e[tid];
    s_wb2[tid] = ((const float4*)wb2)[tid];
  }
  const int es = eidx[m * 256 + (tid >> 1)];
  const int ed = eidx[m * 256 + 128 + (tid >> 1)];
  const int etg = tgt[m * 128 + (tid >> 1)];
  const float q0 = bb2[0], q1 = bb2[1], q2 = bb2[2], q3 = bb2[3];
  __syncthreads();                               // b1: staging visible

  const int xr = rb * 32 + l31;
  const int xswz = (xr & 7) << 4;
  const int cbase = cb * 128;
  f32x16 zero = {};
  f32x16 acc0, acc1, acc2, acc3;

  GEMM4(bufA, wp1p, cbase);        // h1 pre-act
  __syncthreads();                 // b2: all X reads done
  WB_TILE(bufA, acc0, 0, cbase, bp1, 1);
  WB_TILE(bufA, acc1, 1, cbase, bp1, 1);
  WB_TILE(bufA, acc2, 2, cbase, bp1, 1);
  WB_TILE(bufA, acc3, 3, cbase, bp1, 1);
  __syncthreads();                 // b3: h1 visible

  GEMM4(bufA, wctp, cbase);        // hs
  WB_TILE_RAW(bufB, acc0, 0, cbase);
  WB_TILE_RAW(bufB, acc1, 1, cbase);
  WB_TILE_RAW(bufB, acc2, 2, cbase);
  WB_TILE_RAW(bufB, acc3, 3, cbase);
  GEMM4(bufA, wcbp, cbase);        // he (in regs)
  __syncthreads();                 // b4: all h1 reads done
  WB_TILE_RAW(bufA, acc0, 0, cbase);
  WB_TILE_RAW(bufA, acc1, 1, cbase);
  WB_TILE_RAW(bufA, acc2, 2, cbase);
  WB_TILE_RAW(bufA, acc3, 3, cbase);
  __syncthreads();                 // b5: hs/he visible

  // ---- edge phase: thread pair (2t,2t+1) -> edge t, col-halves ----
  {
    const int hf = tid & 1;
    float lg0 = 0.f, lg1 = 0.f, lg2 = 0.f, lg3 = 0.f;
    #pragma unroll
    for (int j = 0; j < 16; ++j) {
      int c0 = hf * 128 + j * 8;
      int offS = ((es << 9) + (c0 << 1)) ^ ((es & 7) << 4);
      int offD = ((ed << 9) + (c0 << 1)) ^ ((ed & 7) << 4);
      uint4 us = *(const uint4*)(bufB + offS);
      uint4 ud = *(const uint4*)(bufA + offD);
      const unsigned* pu = (const unsigned*)&us;
      const unsigned* pv = (const unsigned*)&ud;
      #pragma unroll
      for (int q = 0; q < 4; ++q) {
        unsigned ua = pu[q], ub = pv[q];
        int c = c0 + 2 * q;
        float hlo = bitf(ua << 16) + bitf(ub << 16) + s_bias[c];
        float hhi = bitf(ua & 0xffff0000u) + bitf(ub & 0xffff0000u) + s_bias[c + 1];
        hlo = fmaxf(hlo, 0.f); hhi = fmaxf(hhi, 0.f);
        float4 w0 = s_wb2[c], w1 = s_wb2[c + 1];
        lg0 = fmaf(hlo, w0.x, fmaf(hhi, w1.x, lg0));
        lg1 = fmaf(hlo, w0.y, fmaf(hhi, w1.y, lg1));
        lg2 = fmaf(hlo, w0.z, fmaf(hhi, w1.z, lg2));
        lg3 = fmaf(hlo, w0.w, fmaf(hhi, w1.w, lg3));
      }
    }
    lg0 += __shfl_xor(lg0, 1); lg1 += __shfl_xor(lg1, 1);
    lg2 += __shfl_xor(lg2, 1); lg3 += __shfl_xor(lg3, 1);
    float ce = 0.f, cc = 0.f;
    if (hf == 0) {
      float l0 = lg0 + q0, l1 = lg1 + q1, l2 = lg2 + q2, l3 = lg3 + q3;
      int t = etg;
      int am = 0; float mx = l0;
      if (l1 > mx) { mx = l1; am = 1; }
      if (l2 > mx) { mx = l2; am = 2; }
      if (l3 > mx) { mx = l3; am = 3; }
      float s = __expf(l0 - mx) + __expf(l1 - mx) + __expf(l2 - mx) + __expf(l3 - mx);
      float lt = (t == 0) ? l0 : (t == 1) ? l1 : (t == 2) ? l2 : l3;
      ce = __logf(s) + mx - lt;
      cc = (am == t) ? 1.f : 0.f;
    }
    #pragma unroll
    for (int d = 1; d < 64; d <<= 1) { ce += __shfl_xor(ce, d); cc += __shfl_xor(cc, d); }
    if (lane == 0) { s_red[w * 2] = ce; s_red[w * 2 + 1] = cc; }
    __syncthreads();
    if (tid == 0) {
      atomicAdd(accum + 0, s_red[0] + s_red[2] + s_red[4] + s_red[6]);
      atomicAdd(accum + 1, s_red[1] + s_red[3] + s_red[5] + s_red[7]);
    }
  }
}

// ---------------------------------------------------------------------------
// Atom head: 128 rows/block, 4 waves x 32 rows x 256 cols; named regs only.
// ---------------------------------------------------------------------------
__global__ __launch_bounds__(256, 2) void k_atom(
    const float* __restrict__ node,
    const unsigned short* __restrict__ w1p, const float* __restrict__ b1,
    const unsigned short* __restrict__ w2p, const float* __restrict__ b2,
    const int* __restrict__ tgt, float* __restrict__ accum)
{
  __shared__ __align__(16) unsigned char sm[65536];
  __shared__ float s_red[8];
  const int tid = threadIdx.x;
  const int lane = tid & 63;
  const int w = tid >> 6;
  const int l31 = lane & 31;
  const int h = lane >> 5;
  const long rowbase = (long)blockIdx.x * 128;

  {
    const float* src = node + rowbase * 256;
    #pragma unroll
    for (int it = 0; it < 16; ++it) {
      int lb = (it * 256 + tid) * 16;
      int dst = lb ^ (((lb >> 9) & 7) << 4);
      const float4* s4 = (const float4*)(src + (lb >> 1));
      float4 f0 = s4[0], f1 = s4[1];
      uint4 v = { pack2bf(f0.x, f0.y), pack2bf(f0.z, f0.w),
                  pack2bf(f1.x, f1.y), pack2bf(f1.z, f1.w) };
      *(uint4*)(sm + dst) = v;
    }
  }
  __syncthreads();   // after this, every wave touches only its own rows

  const int xr = w * 32 + l31;
  const int xswz = (xr & 7) << 4;
  f32x16 zero = {};

  // ---- layer 1: 8 col-tiles, depth-1 prefetch, named regs ----
  f32x16 c0 = zero, c1 = zero, c2 = zero, c3 = zero,
         c4 = zero, c5 = zero, c6 = zero, c7 = zero;
  {
    const unsigned char* wb_ = (const unsigned char*)w1p + (l31 << 5) + (h << 4);
    #pragma unroll
    for (int kk = 0; kk < 16; ++kk) {
      bf16x8 bv = *(const bf16x8*)(sm + XADDR(kk));
      const unsigned char* wk = wb_ + (kk << 13);
      uint4 r0 = *(const uint4*)(wk + 0);
      uint4 r1 = *(const uint4*)(wk + 1024);
      uint4 r2 = *(const uint4*)(wk + 2048);
      uint4 r3 = *(const uint4*)(wk + 3072);
      uint4 r4 = *(const uint4*)(wk + 4096);
      uint4 r5 = *(const uint4*)(wk + 5120);
      uint4 r6 = *(const uint4*)(wk + 6144);
      uint4 r7 = *(const uint4*)(wk + 7168);
      c0 = mfma16(as_bf16x8(r0), bv, c0);
      c1 = mfma16(as_bf16x8(r1), bv, c1);
      c2 = mfma16(as_bf16x8(r2), bv, c2);
      c3 = mfma16(as_bf16x8(r3), bv, c3);
      c4 = mfma16(as_bf16x8(r4), bv, c4);
      c5 = mfma16(as_bf16x8(r5), bv, c5);
      c6 = mfma16(as_bf16x8(r6), bv, c6);
      c7 = mfma16(as_bf16x8(r7), bv, c7);
    }
  }
  // relu(+b1) in-place over X (own rows only -> no barrier needed)
  WB_TILE(sm, c0, 0, 0, b1, 1);
  WB_TILE(sm, c1, 1, 0, b1, 1);
  WB_TILE(sm, c2, 2, 0, b1, 1);
  WB_TILE(sm, c3, 3, 0, b1, 1);
  WB_TILE(sm, c4, 4, 0, b1, 1);
  WB_TILE(sm, c5, 5, 0, b1, 1);
  WB_TILE(sm, c6, 6, 0, b1, 1);
  WB_TILE(sm, c7, 7, 0, b1, 1);

  // ---- layer 2: N=128 (4 col-tiles), own rows ----
  f32x16 e0 = zero, e1 = zero, e2 = zero, e3 = zero;
  {
    const unsigned char* wb_ = (const unsigned char*)w2p + (l31 << 5) + (h << 4);
    #pragma unroll
    for (int kk = 0; kk < 16; ++kk) {
      bf16x8 bv = *(const bf16x8*)(sm + XADDR(kk));
      const unsigned char* wk = wb_ + (kk << 12);
      e0 = mfma16(as_bf16x8(*(const uint4*)(wk + 0)), bv, e0);
      e1 = mfma16(as_bf16x8(*(const uint4*)(wk + 1024)), bv, e1);
      e2 = mfma16(as_bf16x8(*(const uint4*)(wk + 2048)), bv, e2);
      e3 = mfma16(as_bf16x8(*(const uint4*)(wk + 3072)), bv, e3);
    }
  }

  // ---- epilogue: lane pair (l, l^32) holds the 118 logits of row xr ----
  long grow = rowbase + xr;
  int t = tgt[grow];
  float mx = -3.0e38f; int am = 0;
  #define EPI_MAX(EV, AB)                                                      \
    _Pragma("unroll")                                                          \
    for (int q = 0; q < 16; ++q) {                                             \
      int col = (AB) + (q & 3) + 8 * (q >> 2) + 4 * h;                         \
      if (col < 118) {                                                         \
        float v = EV[q] + b2[col];                                             \
        EV[q] = v;                                                             \
        if (v > mx) { mx = v; am = col; }                                      \
      }                                                                        \
    }
  EPI_MAX(e0, 0) EPI_MAX(e1, 32) EPI_MAX(e2, 64) EPI_MAX(e3, 96)
  float omx = __shfl_xor(mx, 32); int oam = __shfl_xor(am, 32);
  if (omx > mx || (omx == mx && oam < am)) { mx = omx; am = oam; }
  float s = 0.f;
  #define EPI_SUM(EV, AB)                                                      \
    _Pragma("unroll")                                                          \
    for (int q = 0; q < 16; ++q) {                                             \
      int col = (AB) + (q & 3) + 8 * (q >> 2) + 4 * h;                         \
      if (col < 118) s += __expf(EV[q] - mx);                                  \
    }
  EPI_SUM(e0, 0) EPI_SUM(e1, 32) EPI_SUM(e2, 64) EPI_SUM(e3, 96)
  s += __shfl_xor(s, 32);
  float vt = 0.f;
  #define EPI_TGT(EV, AB)                                                      \
    _Pragma("unroll")                                                          \
    for (int q = 0; q < 16; ++q) {                                             \
      int col = (AB) + (q & 3) + 8 * (q >> 2) + 4 * h;                         \
      if (col < 118 && col == t) vt = EV[q];                                   \
    }
  EPI_TGT(e0, 0) EPI_TGT(e1, 32) EPI_TGT(e2, 64) EPI_TGT(e3, 96)
  vt += __shfl_xor(vt, 32);
  float ce = __logf(s) + mx - vt;
  float cc = (am == t) ? 1.f : 0.f;
  if (h) { ce = 0.f; cc = 0.f; }
  #pragma unroll
  for (int d = 1; d < 64; d <<= 1) { ce += __shfl_xor(ce, d); cc += __shfl_xor(cc, d); }
  if (lane == 0) { s_red[w * 2] = ce; s_red[w * 2 + 1] = cc; }
  __syncthreads();
  if (tid == 0) {
    atomicAdd(accum + 2, s_red[0] + s_red[2] + s_red[4] + s_red[6]);
    atomicAdd(accum + 3, s_red[1] + s_red[3] + s_red[5] + s_red[7]);
  }
}

__global__ __launch_bounds__(64) void k_final(const float* __restrict__ accum,
                                              float* __restrict__ out)
{
  if (threadIdx.x == 0) {
    float bce = accum[0] / 262144.f;
    float bcc = accum[1] / 262144.f;
    float ace = accum[2] / 131072.f;
    float acc_ = accum[3] / 131072.f;
    out[0] = 0.5f * bce + 0.5f * ace;
    out[1] = bcc;
    out[2] = acc_;
  }
}

extern "C" void kernel_launch(void* const* d_in, const int* in_sizes, int n_in,
                              void* d_out, int out_size, void* d_ws, size_t ws_size,
                              hipStream_t stream)
{
  const float* node = (const float*)d_in[0];
  const int* eidx   = (const int*)d_in[1];
  const int* btt    = (const int*)d_in[2];
  const int* att    = (const int*)d_in[3];
  const float* Wp1 = (const float*)d_in[4];
  const float* bp1 = (const float*)d_in[5];
  const float* Wp2 = (const float*)d_in[6];
  const float* bp2 = (const float*)d_in[7];
  const float* Wb1 = (const float*)d_in[8];
  const float* bb1 = (const float*)d_in[9];
  const float* Wb2 = (const float*)d_in[10];
  const float* bb2 = (const float*)d_in[11];
  const float* Wa1 = (const float*)d_in[12];
  const float* ba1 = (const float*)d_in[13];
  const float* Wa2 = (const float*)d_in[14];
  const float* ba2 = (const float*)d_in[15];

  char* ws = (char*)d_ws;
  float* accum = (float*)ws;
  unsigned short* dp1 = (unsigned short*)(ws + 256);
  unsigned short* da1 = (unsigned short*)(ws + 131328);
  unsigned short* da2 = (unsigned short*)(ws + 262400);
  unsigned short* dct = (unsigned short*)(ws + 327936);
  unsigned short* dcb = (unsigned short*)(ws + 459008);
  float* bias_e       = (float*)(ws + 590080);

  k_pack<<<640, 256, 0, stream>>>(Wp1, Wa1, Wa2, dp1, da1, da2, accum);
  k_fold<<<513, 256, 0, stream>>>(Wp2, Wb1, bp2, bb1, dct, dcb, bias_e);
  k_atom<<<1024, 256, 0, stream>>>(node, da1, ba1, da2, ba2, att, accum);
  k_bond<<<2048, 256, 0, stream>>>(node, eidx, btt, dp1, bp1, dct, dcb,
                                   bias_e, Wb2, bb2, accum);
  k_final<<<1, 64, 0, stream>>>(accum, (float*)d_out);
}